// Round 1
// baseline (198.537 us; speedup 1.0000x reference)
//
#include <hip/hip_runtime.h>

#define NJ 8
#define TS 2048
#define NB 1024

__global__ __launch_bounds__(64) void phys_seq_kernel(
    const float4* __restrict__ x,      // (B,T,8) as float4
    const float*  __restrict__ state0, // (B,8,2)
    const float*  __restrict__ M,      // (8,2)
    const float*  __restrict__ inertia,// (8,)
    const float*  __restrict__ damping,// (8,)
    float* __restrict__ out,           // (B,T,8)
    float* __restrict__ muscle,        // (B,8,2,2)
    float* __restrict__ finals)        // (B,8,2)
{
    int tid = blockIdx.x * blockDim.x + threadIdx.x;  // tid = b*8 + j
    if (tid >= NB * NJ) return;
    int b = tid >> 3;
    int j = tid & 7;

    float M0 = M[j * 2 + 0];
    float M1 = M[j * 2 + 1];
    float M20 = M0 * M0;
    float M21 = M1 * M1;
    float d = damping[j];
    float invI = 1.0f / inertia[j];
    const float DT = 1.0f / 60.0f;

    float theta  = state0[tid * 2 + 0];
    float dtheta = state0[tid * 2 + 1];

    const float4* xp = x + (size_t)b * TS * NJ + j;
    float* op = out + (size_t)b * TS * NJ + j;

    #pragma unroll 8
    for (int t = 0; t < TS; ++t) {
        float4 v = xp[(size_t)t * NJ];
        float a = M0 * v.x + M1 * v.y;       // einsum(M, F)
        float c = M20 * v.z + M21 * v.w;     // einsum(M2, K)
        float tau = a - theta * c - d * dtheta;
        float dd = tau * invI;
        dtheta = dtheta + dd * DT;
        theta = theta + dtheta * DT;
        op[(size_t)t * NJ] = theta;
    }

    // final_state (B,8,2)
    finals[tid * 2 + 0] = theta;
    finals[tid * 2 + 1] = dtheta;
    // muscle_states (B,8,2,2): ms[b,j,s,m] = final[b,j,s] * M[j,m]
    muscle[tid * 4 + 0] = theta  * M0;
    muscle[tid * 4 + 1] = theta  * M1;
    muscle[tid * 4 + 2] = dtheta * M0;
    muscle[tid * 4 + 3] = dtheta * M1;
}

extern "C" void kernel_launch(void* const* d_in, const int* in_sizes, int n_in,
                              void* d_out, int out_size, void* d_ws, size_t ws_size,
                              hipStream_t stream) {
    const float4* x      = (const float4*)d_in[0];
    const float*  state0 = (const float*)d_in[1];
    const float*  M      = (const float*)d_in[2];
    const float*  inertia= (const float*)d_in[3];
    const float*  damping= (const float*)d_in[4];

    float* out = (float*)d_out;                          // (B,T,8)
    float* muscle = out + (size_t)NB * TS * NJ;          // (B,8,2,2)
    float* finals = muscle + (size_t)NB * NJ * 2 * 2;    // (B,8,2)

    int total = NB * NJ;  // 8192 threads
    dim3 block(64);
    dim3 grid(total / 64); // 128 blocks -> spread over CUs
    phys_seq_kernel<<<grid, block, 0, stream>>>(x, state0, M, inertia, damping,
                                                out, muscle, finals);
}

// Round 2
// 122.651 us; speedup vs baseline: 1.6187x; 1.6187x over previous
//
#include <hip/hip_runtime.h>

#define NJ 8
#define TS 2048
#define NB 1024
#define CHUNK 64
#define NCHUNK (TS / CHUNK)   // 32
#define DTC (1.0f / 60.0f)

__global__ __launch_bounds__(512, 8) void phys_scan_kernel(
    const float4* __restrict__ x,       // (B,T,8joints) as float4 per joint
    const float*  __restrict__ state0,  // (B,8,2)
    const float*  __restrict__ M,       // (8,2)
    const float*  __restrict__ inertia, // (8,)
    const float*  __restrict__ damping, // (8,)
    float* __restrict__ out,            // (B,T,8)
    float* __restrict__ muscle,         // (B,8,2,2)
    float* __restrict__ finals)         // (B,8,2)
{
    __shared__ float4 lds[2][512];      // 16 KB: double-buffered 64-step chunk

    const int b    = blockIdx.x;
    const int tid  = threadIdx.x;
    const int j    = tid >> 6;          // wave id = joint index
    const int lane = tid & 63;

    const float M0  = M[j * 2 + 0];
    const float M1  = M[j * 2 + 1];
    const float M20 = M0 * M0;
    const float M21 = M1 * M1;
    const float p   = DTC / inertia[j];          // DT / I
    const float g   = 1.0f - p * damping[j];     // dθ self-coefficient

    // carry state (chunk-initial θ, dθ), wave-uniform
    float thc  = state0[(b * NJ + j) * 2 + 0];
    float dthc = state0[(b * NJ + j) * 2 + 1];

    const float4* xb = x + (size_t)b * TS * NJ;  // float4 units
    float* outb = out + (size_t)b * TS * NJ + j; // stride NJ floats per step

    // prologue: stage chunk 0 into registers
    float4 stage = xb[tid];

    for (int ch = 0; ch < NCHUNK; ++ch) {
        const int buf = ch & 1;
        // swizzled LDS write: float4 idx = tid ^ (step&7), step = tid>>3
        lds[buf][tid ^ ((tid >> 3) & 7)] = stage;
        __syncthreads();

        // prefetch next chunk (overlaps with scan compute below)
        if (ch + 1 < NCHUNK) stage = xb[(size_t)(ch + 1) * CHUNK * NJ + tid];

        // read my step's 4 inputs: step = lane, joint = j (swizzled)
        float4 v = lds[buf][(lane * NJ + j) ^ (lane & 7)];

        float a = M0 * v.x + M1 * v.y;    // einsum(M, F_t)
        float c = M20 * v.z + M21 * v.w;  // einsum(M2, K_t)

        // per-step affine map:
        //   dθ' = r0·θ + r1·dθ + rc ;  θ' = s0·θ + s1·dθ + sc
        float r0 = -p * c;
        float r1 = g;
        float rc = p * a;
        float s0 = fmaf(DTC, r0, 1.0f);
        float s1 = DTC * g;
        float sc = DTC * rc;

        // inclusive Kogge-Stone scan over 64 lanes (compose: mine ∘ other)
        #pragma unroll
        for (int delta = 1; delta < 64; delta <<= 1) {
            float o_r0 = __shfl_up(r0, delta, 64);
            float o_r1 = __shfl_up(r1, delta, 64);
            float o_rc = __shfl_up(rc, delta, 64);
            float o_s0 = __shfl_up(s0, delta, 64);
            float o_s1 = __shfl_up(s1, delta, 64);
            float o_sc = __shfl_up(sc, delta, 64);
            if (lane >= delta) {
                float nr0 = fmaf(r0, o_s0, r1 * o_r0);
                float nr1 = fmaf(r0, o_s1, r1 * o_r1);
                float nrc = fmaf(r0, o_sc, fmaf(r1, o_rc, rc));
                float ns0 = fmaf(s0, o_s0, s1 * o_r0);
                float ns1 = fmaf(s0, o_s1, s1 * o_r1);
                float nsc = fmaf(s0, o_sc, fmaf(s1, o_rc, sc));
                r0 = nr0; r1 = nr1; rc = nrc;
                s0 = ns0; s1 = ns1; sc = nsc;
            }
        }

        // apply carry: state after my step
        float th  = fmaf(s0, thc, fmaf(s1, dthc, sc));
        float dth = fmaf(r0, thc, fmaf(r1, dthc, rc));

        // out[b][t0+lane][j] = θ  (L2 merges the 32B-stride scatter)
        outb[(size_t)(ch * CHUNK + lane) * NJ] = th;

        // carry forward lane 63's state
        thc  = __shfl(th, 63, 64);
        dthc = __shfl(dth, 63, 64);

        __syncthreads();  // buf reads done before it is overwritten
    }

    if (lane == 0) {
        const int idx = b * NJ + j;
        finals[idx * 2 + 0] = thc;
        finals[idx * 2 + 1] = dthc;
        muscle[idx * 4 + 0] = thc  * M0;
        muscle[idx * 4 + 1] = thc  * M1;
        muscle[idx * 4 + 2] = dthc * M0;
        muscle[idx * 4 + 3] = dthc * M1;
    }
}

extern "C" void kernel_launch(void* const* d_in, const int* in_sizes, int n_in,
                              void* d_out, int out_size, void* d_ws, size_t ws_size,
                              hipStream_t stream) {
    const float4* x      = (const float4*)d_in[0];
    const float*  state0 = (const float*)d_in[1];
    const float*  M      = (const float*)d_in[2];
    const float*  inertia= (const float*)d_in[3];
    const float*  damping= (const float*)d_in[4];

    float* out    = (float*)d_out;                       // (B,T,8)
    float* muscle = out + (size_t)NB * TS * NJ;          // (B,8,2,2)
    float* finals = muscle + (size_t)NB * NJ * 2 * 2;    // (B,8,2)

    dim3 block(512);          // 8 waves = 8 joints of one batch
    dim3 grid(NB);            // 1024 blocks = 4 blocks/CU, fully resident
    phys_scan_kernel<<<grid, block, 0, stream>>>(x, state0, M, inertia, damping,
                                                 out, muscle, finals);
}